// Round 1
// baseline (228.799 us; speedup 1.0000x reference)
//
#include <hip/hip_runtime.h>

// FIR 4x4 separable depthwise filter, k1=[1,3,3,1], k2=outer(k1,k1)/64.
// Input x: (8, 64, 512, 512) f32 -> 512 planes of 512x512.
// lax SAME padding for kernel 4: pad_lo=1, pad_hi=2 (zero padding).
// out[r][c] = (1/64) * sum_{v=0..3} k1[v] * H[r+v-1][c]
//   H[y][c]  = x[y][c-1] + 3x[y][c] + 3x[y][c+1] + x[y][c+2]

#define FIR_W 512
#define FIR_H 512
#define FIR_ROWS 32   // rows per thread-strip

__device__ __forceinline__ float4 fir_hrow(const float* __restrict__ p, int y, int j) {
    // Horizontal-filtered H for columns 4j..4j+3 of row y; zeros when row is padding.
    float4 h;
    if (y < 0 || y >= FIR_H) {
        h.x = h.y = h.z = h.w = 0.0f;
        return h;
    }
    const float* row = p + (size_t)y * FIR_W;
    const int c = 4 * j;
    const float4 vc = *reinterpret_cast<const float4*>(row + c);
    const float xm1 = (j > 0)             ? row[c - 1] : 0.0f;   // col c-1
    const float xp4 = (j < FIR_W / 4 - 1) ? row[c + 4] : 0.0f;   // col c+4
    const float xp5 = (j < FIR_W / 4 - 1) ? row[c + 5] : 0.0f;   // col c+5
    h.x = xm1  + 3.0f * (vc.x + vc.y) + vc.z;
    h.y = vc.x + 3.0f * (vc.y + vc.z) + vc.w;
    h.z = vc.y + 3.0f * (vc.z + vc.w) + xp4;
    h.w = vc.z + 3.0f * (vc.w + xp4)  + xp5;
    return h;
}

__global__ __launch_bounds__(256) void FIRFilter_88579405512825_kernel(
        const float* __restrict__ x, float* __restrict__ out) {
    const int j     = threadIdx.x;                                // 0..127: col group (4 cols)
    const int strip = blockIdx.x * blockDim.y + threadIdx.y;      // 0..15: 32-row strip
    const int plane = blockIdx.y;                                 // 0..511: (b, c) plane

    const float* p = x   + (size_t)plane * (FIR_W * FIR_H);
    float*       q = out + (size_t)plane * (FIR_W * FIR_H);

    const int r0 = strip * FIR_ROWS;

    // Rolling window of horizontal-filtered rows: need H(r-1..r+2) for output row r.
    float4 h1 = fir_hrow(p, r0 - 1, j);
    float4 h2 = fir_hrow(p, r0,     j);
    float4 h3 = fir_hrow(p, r0 + 1, j);

    const float s = 1.0f / 64.0f;

    #pragma unroll 4
    for (int r = r0; r < r0 + FIR_ROWS; ++r) {
        float4 h0 = h1; h1 = h2; h2 = h3;
        h3 = fir_hrow(p, r + 2, j);

        float4 o;
        o.x = (h0.x + 3.0f * (h1.x + h2.x) + h3.x) * s;
        o.y = (h0.y + 3.0f * (h1.y + h2.y) + h3.y) * s;
        o.z = (h0.z + 3.0f * (h1.z + h2.z) + h3.z) * s;
        o.w = (h0.w + 3.0f * (h1.w + h2.w) + h3.w) * s;

        *reinterpret_cast<float4*>(q + (size_t)r * FIR_W + 4 * j) = o;
    }
}

extern "C" void kernel_launch(void* const* d_in, const int* in_sizes, int n_in,
                              void* d_out, int out_size, void* d_ws, size_t ws_size,
                              hipStream_t stream) {
    const float* x = (const float*)d_in[0];
    float* out = (float*)d_out;

    const int planes = in_sizes[0] / (FIR_W * FIR_H);   // 8*64 = 512

    // block: 128 threads across width (4 cols each) x 2 row-strips = 256 threads
    dim3 block(128, 2);
    // grid.x: 512 rows / (32 rows * 2 strips) = 8 ; grid.y: planes
    dim3 grid(FIR_H / (FIR_ROWS * 2), planes);

    FIRFilter_88579405512825_kernel<<<grid, block, 0, stream>>>(x, out);
}